// Round 2
// baseline (448.660 us; speedup 1.0000x reference)
//
#include <hip/hip_runtime.h>

// Fused 16-expert, 2-layer Linear+ReLU stack, v3 (persistent, barrier-free).
//   x  [524288, 128] fp32 -> 16 slices of 32768 tokens
//   W  [16, 2, 128, 128] fp32 (torch [out,in]) ; b [16, 2, 128] fp32
//
// v3 strategy (on top of v2's fragment-major W + swapped-operand MFMA):
//  - prologue kernel converts W once to bf16 fragment-major layout (g_Wf).
//  - persistent blocks: 512 blocks x 512 thr; each block owns 8 consecutive
//    128-token tiles of one model. W0+W1+bias staged into LDS ONCE, one
//    __syncthreads, then 8 tiles with ZERO barriers:
//      * sY has its own buffer (no W0 overlay) and is accessed only by the
//        4 lanes sharing ln within one wave -> wave-private; per-wave LDS
//        ordering + compiler memory clobbers replace __syncthreads.
//  - register x prefetch: tile i's x is converted to bf16 at tile start
//    (freeing the fp32 regs), then tile i+1's loads are issued -> a full
//    tile of compute (~800 cyc) covers HBM latency.
//  - bias preloaded as MFMA C-in (acc init = bias), removing epilogue adds.
//  - LDS: 32K (W0) + 32K (W1) + 34.8K (sY) + 1K (sB) = 99 KB -> 1 blk/CU.

#define NF    128
#define NM    16
#define NTOK  524288
#define TPM   (NTOK / NM)      // 32768 tokens per model
#define BM    128              // tokens per tile
#define TILES 8                // tiles per block
#define BLKPM ((TPM / BM) / TILES)   // 32 blocks per model
#define WPAD  136              // sY row pitch in bf16 elems (272B, 16B-aligned)

typedef __attribute__((ext_vector_type(8))) short bf16x8;
typedef __attribute__((ext_vector_type(4))) short bf16x4v;
typedef __attribute__((ext_vector_type(4))) float f32x4;
typedef unsigned int u32;

__device__ __forceinline__ unsigned short f2bf(float f) {
    union { float f; unsigned u; } v; v.f = f;
    unsigned r = v.u + 0x7FFFu + ((v.u >> 16) & 1u);   // RNE
    return (unsigned short)(r >> 16);
}

// bf16 W in fragment-major layout: [m][l][fid=gt*4+kt][lane][8 elems]
__device__ alignas(16) unsigned short g_Wf[NM * 2 * NF * NF];   // 1 MiB

__global__ __launch_bounds__(256) void convw_kernel(const float* __restrict__ W) {
    const int idx  = blockIdx.x * 256 + threadIdx.x;  // 65536 fragment-lanes
    const int lane = idx & 63;
    const int fid  = (idx >> 6) & 31;
    const int ml   = idx >> 11;                       // m*2 + l
    const int row  = (fid >> 2) * 16 + (lane & 15);   // out-feature
    const int col  = (fid & 3) * 32 + (lane >> 4) * 8;// in-feature (k)
    const float* s = W + ((size_t)ml * NF + row) * NF + col;
    float4 a = *(const float4*)s;
    float4 c = *(const float4*)(s + 4);
    unsigned short* d = &g_Wf[(size_t)idx * 8];
    d[0] = f2bf(a.x); d[1] = f2bf(a.y); d[2] = f2bf(a.z); d[3] = f2bf(a.w);
    d[4] = f2bf(c.x); d[5] = f2bf(c.y); d[6] = f2bf(c.z); d[7] = f2bf(c.w);
}

__device__ __forceinline__ void load_lds16(const unsigned short* g, unsigned short* l) {
    __builtin_amdgcn_global_load_lds(
        (const __attribute__((address_space(1))) u32*)g,
        (__attribute__((address_space(3))) u32*)l, 16, 0, 0);
}

__global__ __launch_bounds__(512, 2) void mlp16_kernel(
        const float* __restrict__ x, const float* __restrict__ b,
        float* __restrict__ out) {
    __shared__ alignas(16) unsigned short sW0[NF * NF];   // 32768 B
    __shared__ alignas(16) unsigned short sW1[NF * NF];   // 32768 B
    __shared__ alignas(16) unsigned short sY[BM * WPAD];  // 34816 B
    __shared__ alignas(16) float sB[2 * NF];              // 1024 B

    const int t    = threadIdx.x;
    const int w    = t >> 6;       // wave 0..7, owns tokens w*16..w*16+15
    const int lane = t & 63;
    const int ln   = lane & 15;    // token within wave's 16-group
    const int q    = lane >> 4;    // k-octet / feature-quad select

    const int m  = blockIdx.x / BLKPM;
    const int tg = blockIdx.x % BLKPM;

    if (t < 2 * NF) sB[t] = b[m * 2 * NF + t];

    // ---- stage W0 + W1 fragments once (wave w: fids w*4..w*4+3) ----
    const unsigned short* wsrc = g_Wf + (size_t)m * 2 * NF * NF;
    #pragma unroll
    for (int i = 0; i < 4; ++i) {
        const int fid = w * 4 + i;
        load_lds16(wsrc + (size_t)(fid * 64 + lane) * 8, &sW0[fid * 512]);
        load_lds16(wsrc + NF * NF + (size_t)(fid * 64 + lane) * 8, &sW1[fid * 512]);
    }

    const size_t tok0 = (size_t)m * TPM + (size_t)tg * (TILES * BM);
    const float* xrow = x + (tok0 + (size_t)(w * 16 + ln)) * NF;
    float*       orow = out + (tok0 + (size_t)(w * 16 + ln)) * NF;
    unsigned short*       syw = &sY[(w * 16 + ln) * WPAD];
    const unsigned short* syr = syw;

    // ---- prefetch tile 0 x into regs (hides W staging latency) ----
    float4 xa[8];
    #pragma unroll
    for (int kt = 0; kt < 4; ++kt) {
        xa[2 * kt]     = *(const float4*)(xrow + kt * 32 + q * 8);
        xa[2 * kt + 1] = *(const float4*)(xrow + kt * 32 + q * 8 + 4);
    }

    __syncthreads();   // the ONLY barrier: W/sB staging complete

    for (int i = 0; i < TILES; ++i) {
        // -- convert tile-i x to bf16 fragments (frees xa) --
        bf16x8 xb[4];
        #pragma unroll
        for (int kt = 0; kt < 4; ++kt) {
            const float4 a0 = xa[2 * kt], a1 = xa[2 * kt + 1];
            bf16x8 v;
            v[0] = (short)f2bf(a0.x); v[1] = (short)f2bf(a0.y);
            v[2] = (short)f2bf(a0.z); v[3] = (short)f2bf(a0.w);
            v[4] = (short)f2bf(a1.x); v[5] = (short)f2bf(a1.y);
            v[6] = (short)f2bf(a1.z); v[7] = (short)f2bf(a1.w);
            xb[kt] = v;
        }

        // -- issue tile i+1 x loads (covered by this tile's compute) --
        if (i + 1 < TILES) {
            const float* p = xrow + (size_t)(i + 1) * (BM * NF);
            #pragma unroll
            for (int kt = 0; kt < 4; ++kt) {
                xa[2 * kt]     = *(const float4*)(p + kt * 32 + q * 8);
                xa[2 * kt + 1] = *(const float4*)(p + kt * 32 + q * 8 + 4);
            }
        }

        // -- layer 1: A = W0 fragment, B = x fragment, C-in = bias --
        f32x4 acc[8];
        #pragma unroll
        for (int gt = 0; gt < 8; ++gt) acc[gt] = *(const f32x4*)&sB[gt * 16 + q * 4];
        #pragma unroll
        for (int kt = 0; kt < 4; ++kt) {
            #pragma unroll
            for (int gt = 0; gt < 8; ++gt) {
                bf16x8 wf = *(const bf16x8*)&sW0[((gt * 4 + kt) * 64 + lane) * 8];
                acc[gt] = __builtin_amdgcn_mfma_f32_16x16x32_bf16(wf, xb[kt], acc[gt], 0, 0, 0);
            }
        }

        // -- relu -> sY (wave-private rows; no barrier needed) --
        #pragma unroll
        for (int gt = 0; gt < 8; ++gt) {
            bf16x4v yv;
            #pragma unroll
            for (int r = 0; r < 4; ++r) {
                float vv = acc[gt][r];
                vv = vv > 0.f ? vv : 0.f;
                yv[r] = (short)f2bf(vv);
            }
            *(bf16x4v*)&syw[gt * 16 + q * 4] = yv;
        }
        // compiler-level fence: keep cross-lane sY reads after the writes
        asm volatile("" ::: "memory");

        // -- layer 2: A = W1 fragment, B = sY fragment, C-in = bias --
        f32x4 acc2[8];
        #pragma unroll
        for (int gt = 0; gt < 8; ++gt) acc2[gt] = *(const f32x4*)&sB[NF + gt * 16 + q * 4];
        #pragma unroll
        for (int kt = 0; kt < 4; ++kt) {
            const bf16x8 yb = *(const bf16x8*)(syr + kt * 32 + q * 8);
            #pragma unroll
            for (int gt = 0; gt < 8; ++gt) {
                bf16x8 wf = *(const bf16x8*)&sW1[((gt * 4 + kt) * 64 + lane) * 8];
                acc2[gt] = __builtin_amdgcn_mfma_f32_16x16x32_bf16(wf, yb, acc2[gt], 0, 0, 0);
            }
        }
        // fence: next iteration's sY writes must stay after these reads
        asm volatile("" ::: "memory");

        // -- relu -> global out: coalesced float4 per gt --
        float* op = orow + (size_t)i * (BM * NF);
        #pragma unroll
        for (int gt = 0; gt < 8; ++gt) {
            float4 o;
            float v0 = acc2[gt][0]; o.x = v0 > 0.f ? v0 : 0.f;
            float v1 = acc2[gt][1]; o.y = v1 > 0.f ? v1 : 0.f;
            float v2 = acc2[gt][2]; o.z = v2 > 0.f ? v2 : 0.f;
            float v3 = acc2[gt][3]; o.w = v3 > 0.f ? v3 : 0.f;
            *(float4*)(op + gt * 16 + q * 4) = o;
        }
    }
}

extern "C" void kernel_launch(void* const* d_in, const int* in_sizes, int n_in,
                              void* d_out, int out_size, void* d_ws, size_t ws_size,
                              hipStream_t stream) {
    const float* x = (const float*)d_in[0];
    const float* W = (const float*)d_in[1];
    const float* b = (const float*)d_in[2];
    float* out = (float*)d_out;
    convw_kernel<<<dim3(256), dim3(256), 0, stream>>>(W);
    mlp16_kernel<<<dim3(NM * BLKPM), dim3(512), 0, stream>>>(x, b, out);
}